// Round 2
// baseline (1894.838 us; speedup 1.0000x reference)
//
#include <hip/hip_runtime.h>

// Problem dims (fixed by setup_inputs)
#define B_  4
#define L_  2048
#define D_  2048
#define R_  2560
#define BL_ (B_ * L_)
#define LP_ (L_ + 6)          // padded L for conv shifts (3 each side)

#define CHK_  16              // scan chunks along L
#define CLEN_ (L_ / CHK_)     // 128

typedef unsigned short u16;
typedef unsigned int   u32;

typedef __attribute__((ext_vector_type(8))) short short8;
typedef __attribute__((ext_vector_type(4))) float f32x4;

static __device__ __forceinline__ u16 f2bf(float f) {
  u32 x = __float_as_uint(f);
  x += 0x7fffu + ((x >> 16) & 1u);   // round-to-nearest-even
  return (u16)(x >> 16);
}
static __device__ __forceinline__ float bf2f(u16 u) {
  return __uint_as_float(((u32)u) << 16);
}

// async global->LDS, 16B per lane; LDS dest = wave-uniform base + lane*16
static __device__ __forceinline__ void gld16(const u16* g, u16* l) {
  __builtin_amdgcn_global_load_lds(
      (const __attribute__((address_space(1))) void*)g,
      (__attribute__((address_space(3))) void*)l, 16, 0, 0);
}

#define SB0()     __builtin_amdgcn_sched_barrier(0)
#define BAR()     __builtin_amdgcn_s_barrier()
#define LGKM0()   do { asm volatile("s_waitcnt lgkmcnt(0)" ::: "memory"); SB0(); } while (0)

// ---------------- conversions ----------------
__global__ void cvt_bf16(const float* __restrict__ src, u16* __restrict__ dst, int n) {
  int i = blockIdx.x * blockDim.x + threadIdx.x;
  int stride = gridDim.x * blockDim.x;
  for (; i < n; i += stride) dst[i] = f2bf(src[i]);
}

// conv_w [R,R,4] fp32 -> 4 planes of [R,R] bf16 (tap-major)
__global__ void cvt_convw(const float* __restrict__ cw, u16* __restrict__ out) {
  int i = blockIdx.x * blockDim.x + threadIdx.x;  // over R_*R_ (o*R + iin)
  if (i >= R_ * R_) return;
  const float4 v = *(const float4*)(cw + (size_t)i * 4);
  out[(size_t)0 * R_ * R_ + i] = f2bf(v.x);
  out[(size_t)1 * R_ * R_ + i] = f2bf(v.y);
  out[(size_t)2 * R_ * R_ + i] = f2bf(v.z);
  out[(size_t)3 * R_ * R_ + i] = f2bf(v.w);
}

// zero the 3+3 pad rows per batch of padded h1 [B][LP_][R]
__global__ void zero_pads(u16* __restrict__ h1p) {
  int i = blockIdx.x * blockDim.x + threadIdx.x;   // over 24*R_
  if (i >= 24 * R_) return;
  const int rr = i / R_, c = i % R_;
  const int b = rr / 6, k = rr % 6;
  const int row = b * LP_ + (k < 3 ? k : L_ + k);  // rows 0..2 and 2051..2053
  h1p[(size_t)row * R_ + c] = 0;
}

// ---------------- 256-wide 8-phase GEMM ----------------
// C[M, N] = act(A[M,K] * Bm[N,K]^T + bias[N]), bf16 in, fp32 accum.
// BM=256, BN=NF*64 (NF=5 -> 320, NF=4 -> 256), BK=64. 512 threads = 8 waves (2M x 4N).
// Per wave: 128 rows x NF*16 cols = acc[8][NF] of 16x16 frags. 4 phases per K-tile:
//   ph0: ds_read A(M-half0,k0)+B(all,k0); stage A1(t+1)            ; MFMA M0 x k0
//   ph1: ds_read A(M-half0,k1)+B(all,k1)                           ; MFMA M0 x k1
//   ph2: ds_read A(M-half1,k0); stage A0(t+2)+B0,B1(t+2)           ; MFMA M1 x k0
//   ph3: ds_read A(M-half1,k1); stage B2..(t+2); vmcnt(7|6)        ; MFMA M1 x k1
// Each phase: [reads; stages; s_barrier; lgkmcnt(0); setprio(1); MFMA; setprio(0); s_barrier].
// Counted vmcnt once per K-tile (in-order retirement => completes exactly K-tile t+1's
// stages). LDS layout per buffer: A halves [128][64] + NF B chunks [64][64], rows 128B,
// chunk-XOR swizzle c^(row&7) applied to the stage SOURCE address and the ds_read (both-
// sides rule). Stage dest is the wave-uniform base (global_load_lds scatters lane*16).
// TAPS=4: A is padded h1 ([B][LP_][R]); K-tile u -> tap=u/NTK, shift 2*tap-3; B plane per tap.
// Tail: stage indices clamped to NT-1 (benign duplicate writes to dead/identical regions),
// keeps vmcnt counting uniform.
//
// __launch_bounds__(512) ONLY (no min-waves arg): acc[8][5]=160 VGPR + frags ~56 needs the
// full 256-VGPR/wave budget (2 waves/SIMD). The (512,2) variant capped VGPRs at 128 and
// spilled the whole accumulator to scratch (WRITE_SIZE 41MB -> 637MB). LDS=144KB means
// 1 block/CU regardless, so nothing is lost.
template <int NF, int IB>
__device__ __forceinline__ void mfma_block(f32x4 (&acc)[8][NF], const short8 (&aF)[4],
                                           const short8 (&bF)[NF]) {
#pragma unroll
  for (int i = 0; i < 4; ++i)
#pragma unroll
    for (int j = 0; j < NF; ++j)
      acc[IB + i][j] =
          __builtin_amdgcn_mfma_f32_16x16x32_bf16(aF[i], bF[j], acc[IB + i][j], 0, 0, 0);
}

template <int KDIM, int TAPS, int NF, int ACT, int OBF16, int PADOUT>
__global__ __launch_bounds__(512)
void gemm256(const u16* __restrict__ A, const u16* __restrict__ Bm,
             const float* __restrict__ bias, void* __restrict__ Cv, int N) {
  constexpr int NTK = KDIM / 64;
  constexpr int NT  = NTK * TAPS;
  constexpr int BN  = NF * 64;
  constexpr int BUFU16 = 16384 + NF * 4096;      // u16 per buffer (A 32KB + B NF*8KB)
  __shared__ u16 lds[2][BUFU16];

  const int tid  = threadIdx.x;
  const int wave = tid >> 6, lane = tid & 63;
  const int wr = wave >> 2, wc = wave & 3;       // 2 x 4 wave grid
  const int q = lane >> 4, r16 = lane & 15;
  const int rsw = r16 & 7;
  const int bm = blockIdx.x * 256, bn = blockIdx.y * BN;
  const int srow = tid >> 3;                     // 0..63 staging row
  const int schunk = (tid & 7) ^ (srow & 7);     // pre-swizzled source chunk
  const int bbatch = bm >> 11;                   // batch (L_=2048, BM=256 divides)
  const int arow0 = (TAPS == 4) ? (bm + 3 + 6 * bbatch) : bm;

  f32x4 acc[8][NF] = {};

  auto stA = [&](int u, int h) {                 // one A half-tile (128 rows): 2 issues
    const int uc = (u < NT) ? u : (NT - 1);
    const int tap = uc / NTK;
    const int ku  = (uc % NTK) * 64;
    const int sh  = (TAPS == 4) ? (2 * tap - 3) : 0;
    const u16* src = A + (size_t)(arow0 + sh + h * 128) * KDIM + ku + schunk * 8;
    u16* dst = &lds[u & 1][h * 8192 + wave * 512];
#pragma unroll
    for (int s = 0; s < 2; ++s)
      gld16(src + (size_t)(s * 64 + srow) * KDIM, dst + s * 4096);
  };
  auto stB = [&](int u, int j) {                 // one B chunk (64 N-rows): 1 issue
    const int uc = (u < NT) ? u : (NT - 1);
    const int tap = uc / NTK;
    const int ku  = (uc % NTK) * 64;
    const u16* src = Bm + (size_t)tap * R_ * R_ +
                     (size_t)(bn + j * 64 + srow) * KDIM + ku + schunk * 8;
    gld16(src, &lds[u & 1][16384 + j * 4096 + wave * 512]);
  };
  auto ldA = [&](short8 (&f)[4], int p, int half, int k) {
    const int base = half * 8192 + (wr * 64 + r16) * 64 + ((k * 4 + q) ^ rsw) * 8;
#pragma unroll
    for (int i = 0; i < 4; ++i)
      f[i] = *(const short8*)&lds[p][base + i * 1024];
  };
  auto ldB = [&](short8 (&f)[NF], int p, int k) {
    const int base = 16384 + (wc * 16 + r16) * 64 + ((k * 4 + q) ^ rsw) * 8;
#pragma unroll
    for (int j = 0; j < NF; ++j)
      f[j] = *(const short8*)&lds[p][base + j * 4096];
  };

  // ---- prologue: K-tile0 fully + K-tile1 (A0 + B); A1(1) arrives in t=0 ph0
  stA(0, 0); stA(0, 1);
#pragma unroll
  for (int j = 0; j < NF; ++j) stB(0, j);
  stA(1, 0);
#pragma unroll
  for (int j = 0; j < NF; ++j) stB(1, j);
  if constexpr (NF == 5) asm volatile("s_waitcnt vmcnt(7)" ::: "memory");
  else                   asm volatile("s_waitcnt vmcnt(6)" ::: "memory");
  SB0();
  BAR();

  short8 aF[4], bF0[NF], bF1[NF];
  for (int t = 0; t < NT; ++t) {
    const int p = t & 1;
    // ---- phase 0
    ldA(aF, p, 0, 0);
    ldB(bF0, p, 0);
    stA(t + 1, 1);
    BAR(); LGKM0();
    __builtin_amdgcn_s_setprio(1);
    mfma_block<NF, 0>(acc, aF, bF0);
    __builtin_amdgcn_s_setprio(0);
    SB0(); BAR();
    // ---- phase 1
    ldA(aF, p, 0, 1);
    ldB(bF1, p, 1);
    BAR(); LGKM0();
    __builtin_amdgcn_s_setprio(1);
    mfma_block<NF, 0>(acc, aF, bF1);
    __builtin_amdgcn_s_setprio(0);
    SB0(); BAR();
    // ---- phase 2
    ldA(aF, p, 1, 0);
    stA(t + 2, 0);
    stB(t + 2, 0); stB(t + 2, 1);
    BAR(); LGKM0();
    __builtin_amdgcn_s_setprio(1);
    mfma_block<NF, 4>(acc, aF, bF0);
    __builtin_amdgcn_s_setprio(0);
    SB0(); BAR();
    // ---- phase 3
    ldA(aF, p, 1, 1);
#pragma unroll
    for (int j = 2; j < NF; ++j) stB(t + 2, j);
    BAR(); LGKM0();
    __builtin_amdgcn_s_setprio(1);
    mfma_block<NF, 4>(acc, aF, bF1);
    __builtin_amdgcn_s_setprio(0);
    if constexpr (NF == 5) asm volatile("s_waitcnt vmcnt(7)" ::: "memory");
    else                   asm volatile("s_waitcnt vmcnt(6)" ::: "memory");
    SB0(); BAR();
  }

  // ---- epilogue
#pragma unroll
  for (int i = 0; i < 8; ++i) {
    const int rb  = ((i & 4) ? 128 : 0) + wr * 64 + (i & 3) * 16;
    const int row = bm + rb + q * 4;
    const int orow = PADOUT ? (row + 3 + 6 * bbatch) : row;
#pragma unroll
    for (int j = 0; j < NF; ++j) {
      const int col = bn + j * 64 + wc * 16 + r16;
      const float bv = bias[col];
#pragma unroll
      for (int rr = 0; rr < 4; ++rr) {
        float v = acc[i][j][rr] + bv;
        if (ACT == 1) v = v / (1.f + __expf(-v));
        const size_t off = (size_t)(orow + rr) * N + col;
        if (OBF16) ((u16*)Cv)[off] = f2bf(v);
        else       ((float*)Cv)[off] = v;
      }
    }
  }
}

// ---------------- RG-LRU elementwise: build (a, b) fp32 ----------------
__global__ void gate_ew(const u16* __restrict__ gab, const u16* __restrict__ gib,
                        const u16* __restrict__ h2b, const float* __restrict__ lam,
                        float* __restrict__ a32, float* __restrict__ b32) {
  int idx = blockIdx.x * blockDim.x + threadIdx.x;
  if (idx >= BL_ * R_) return;
  const int r = idx % R_;
  const float ga = bf2f(gab[idx]);
  const float gi = bf2f(gib[idx]);
  const float h2 = bf2f(h2b[idx]);
  const float rr = 1.f / (1.f + __expf(-ga));
  const float ii = 1.f / (1.f + __expf(-gi));
  const float lm = lam[r];
  const float sp = log1pf(__expf(lm));          // softplus, lam in [0.5,2]
  const float log_a = -8.f * rr * sp;
  const float a  = __expf(log_a);
  const float e2 = __expf(2.f * log_a);
  const float mult = sqrtf(fmaxf(1.f - e2, 0.f));
  a32[idx] = a;
  b32[idx] = mult * ii * h2;
}

// ---------------- chunked scan: 3 passes ----------------
__global__ void scan_pass1(const float* __restrict__ a32, const float* __restrict__ b32,
                           float* __restrict__ Aprod, float* __restrict__ Hend) {
  int t = blockIdx.x * blockDim.x + threadIdx.x;   // over CHK_*B_*R_
  if (t >= CHK_ * B_ * R_) return;
  const int c = t / (B_ * R_), br = t % (B_ * R_);
  const int b = br / R_, r = br % R_;
  size_t idx = ((size_t)b * L_ + c * CLEN_) * R_ + r;
  float Ap = 1.f, h = 0.f;
  for (int l = 0; l < CLEN_; ++l) {
    const float a = a32[idx], bb = b32[idx];
    Ap *= a;
    h = a * h + bb;
    idx += R_;
  }
  Aprod[t] = Ap;
  Hend[t]  = h;
}

__global__ void scan_pass2(const float* __restrict__ Aprod, float* __restrict__ Hend) {
  int br = blockIdx.x * blockDim.x + threadIdx.x;
  if (br >= B_ * R_) return;
  float h = Hend[br];                               // chunk 0 end state
  for (int c = 1; c < CHK_; ++c) {
    const int i = c * (B_ * R_) + br;
    h = Hend[i] + Aprod[i] * h;
    Hend[i] = h;
  }
}

__global__ void scan_pass3(const float* __restrict__ a32, const float* __restrict__ b32,
                           const float* __restrict__ Hend, u16* __restrict__ hs) {
  int t = blockIdx.x * blockDim.x + threadIdx.x;
  if (t >= CHK_ * B_ * R_) return;
  const int c = t / (B_ * R_), br = t % (B_ * R_);
  const int b = br / R_, r = br % R_;
  float h = (c == 0) ? 0.f : Hend[(size_t)(c - 1) * (B_ * R_) + br];
  size_t idx = ((size_t)b * L_ + c * CLEN_) * R_ + r;
  for (int l = 0; l < CLEN_; ++l) {
    h = a32[idx] * h + b32[idx];
    hs[idx] = f2bf(h);
    idx += R_;
  }
}

// ---------------- launcher ----------------
extern "C" void kernel_launch(void* const* d_in, const int* in_sizes, int n_in,
                              void* d_out, int out_size, void* d_ws, size_t ws_size,
                              hipStream_t stream) {
  (void)in_sizes; (void)n_in; (void)out_size; (void)ws_size;
  const float* x   = (const float*)d_in[0];
  const float* w1  = (const float*)d_in[1];
  const float* b1  = (const float*)d_in[2];
  const float* cw  = (const float*)d_in[3];
  const float* cb  = (const float*)d_in[4];
  const float* wa  = (const float*)d_in[5];
  const float* ba  = (const float*)d_in[6];
  const float* wx  = (const float*)d_in[7];
  const float* bx  = (const float*)d_in[8];
  const float* lam = (const float*)d_in[9];
  const float* w2  = (const float*)d_in[10];
  const float* b2  = (const float*)d_in[11];

  char* ws = (char*)d_ws;
  size_t o = 0;
  auto alloc = [&](size_t bytes) { char* p = ws + o; o += (bytes + 255) & ~255ull; return p; };

  u16* w2b = (u16*)alloc((size_t)D_ * R_ * 2);
  u16* wab = (u16*)alloc((size_t)R_ * R_ * 2);
  u16* wxb = (u16*)alloc((size_t)R_ * R_ * 2);
  char* a32p = ws + o;                       // overlay: xb+w1b+cwb (dead by then) = 96.5MB >= 84MB
  u16* xb  = (u16*)alloc((size_t)BL_ * D_ * 2);
  u16* w1b = (u16*)alloc((size_t)R_ * D_ * 2);
  u16* cwb = (u16*)alloc((size_t)4 * R_ * R_ * 2);
  char* b32p = ws + o;                       // overlay: h1p (dead after conv) + extra = 84MB
  u16* h1p = (u16*)alloc((size_t)B_ * LP_ * R_ * 2);          // padded h1
  alloc((size_t)BL_ * R_ * 4 - (size_t)B_ * LP_ * R_ * 2);    // extra tail of b32 overlay
  u16* h2b = (u16*)alloc((size_t)BL_ * R_ * 2);
  u16* gab = (u16*)alloc((size_t)BL_ * R_ * 2);
  u16* gib = (u16*)alloc((size_t)BL_ * R_ * 2);
  float* Aprod = (float*)alloc((size_t)CHK_ * B_ * R_ * 4);
  float* Hend  = (float*)alloc((size_t)CHK_ * B_ * R_ * 4);
  float* a32 = (float*)a32p;
  float* b32 = (float*)b32p;
  u16* hsb = gab;                            // reuse after gate_ew consumed it

  cvt_bf16<<<4096, 256, 0, stream>>>(x,  xb,  BL_ * D_);
  cvt_bf16<<<2048, 256, 0, stream>>>(w1, w1b, R_ * D_);
  cvt_bf16<<<2048, 256, 0, stream>>>(wa, wab, R_ * R_);
  cvt_bf16<<<2048, 256, 0, stream>>>(wx, wxb, R_ * R_);
  cvt_bf16<<<2048, 256, 0, stream>>>(w2, w2b, D_ * R_);
  cvt_convw<<<(R_ * R_ + 255) / 256, 256, 0, stream>>>(cw, cwb);
  zero_pads<<<(24 * R_ + 255) / 256, 256, 0, stream>>>(h1p);

  // linear1 + silu -> padded h1 (rows +3+6*batch)
  gemm256<2048, 1, 5, 1, 1, 1><<<dim3(32, 8), 512, 0, stream>>>(xb, w1b, b1, h1p, R_);
  // temporal conv: K' = 4*R GEMM over padded h1 (tap folded into K-tiles)
  gemm256<2560, 4, 5, 0, 1, 0><<<dim3(32, 8), 512, 0, stream>>>(h1p, cwb, cb, h2b, R_);
  // gates
  gemm256<2560, 1, 5, 0, 1, 0><<<dim3(32, 8), 512, 0, stream>>>(h2b, wab, ba, gab, R_);
  gemm256<2560, 1, 5, 0, 1, 0><<<dim3(32, 8), 512, 0, stream>>>(h2b, wxb, bx, gib, R_);
  // a,b for recurrence
  gate_ew<<<(BL_ * R_ + 255) / 256, 256, 0, stream>>>(gab, gib, h2b, lam, a32, b32);
  // linear recurrence (chunked, 3 passes)
  scan_pass1<<<(CHK_ * B_ * R_ + 255) / 256, 256, 0, stream>>>(a32, b32, Aprod, Hend);
  scan_pass2<<<(B_ * R_ + 255) / 256, 256, 0, stream>>>(Aprod, Hend);
  scan_pass3<<<(CHK_ * B_ * R_ + 255) / 256, 256, 0, stream>>>(a32, b32, Hend, hsb);
  // linear2 -> d_out (fp32), N=2048 uses NF=4 (grid 32x8 exact)
  gemm256<2560, 1, 4, 0, 0, 0><<<dim3(32, 8), 512, 0, stream>>>(hsb, w2b, b2, d_out, D_);
}

// Round 3
// 1617.859 us; speedup vs baseline: 1.1712x; 1.1712x over previous
//
#include <hip/hip_runtime.h>

// Problem dims (fixed by setup_inputs)
#define B_  4
#define L_  2048
#define D_  2048
#define R_  2560
#define BL_ (B_ * L_)
#define LP_ (L_ + 6)          // padded L for conv shifts (3 each side)

#define CHK_  16              // scan chunks along L
#define CLEN_ (L_ / CHK_)     // 128

typedef unsigned short u16;
typedef unsigned int   u32;

typedef __attribute__((ext_vector_type(8))) short short8;
typedef __attribute__((ext_vector_type(4))) float f32x4;

static __device__ __forceinline__ u16 f2bf(float f) {
  u32 x = __float_as_uint(f);
  x += 0x7fffu + ((x >> 16) & 1u);   // round-to-nearest-even
  return (u16)(x >> 16);
}
static __device__ __forceinline__ float bf2f(u16 u) {
  return __uint_as_float(((u32)u) << 16);
}

// async global->LDS, 16B per lane; LDS dest = wave-uniform base + lane*16
static __device__ __forceinline__ void gld16(const u16* g, u16* l) {
  __builtin_amdgcn_global_load_lds(
      (const __attribute__((address_space(1))) void*)g,
      (__attribute__((address_space(3))) void*)l, 16, 0, 0);
}

#define SB0()     __builtin_amdgcn_sched_barrier(0)
#define BAR()     __builtin_amdgcn_s_barrier()
#define LGKM0()   do { asm volatile("s_waitcnt lgkmcnt(0)" ::: "memory"); SB0(); } while (0)

// ---------------- conversions ----------------
__global__ void cvt_bf16(const float* __restrict__ src, u16* __restrict__ dst, int n) {
  int i = blockIdx.x * blockDim.x + threadIdx.x;
  int stride = gridDim.x * blockDim.x;
  for (; i < n; i += stride) dst[i] = f2bf(src[i]);
}

// conv_w [R,R,4] fp32 -> 4 planes of [R,R] bf16 (tap-major)
__global__ void cvt_convw(const float* __restrict__ cw, u16* __restrict__ out) {
  int i = blockIdx.x * blockDim.x + threadIdx.x;  // over R_*R_ (o*R + iin)
  if (i >= R_ * R_) return;
  const float4 v = *(const float4*)(cw + (size_t)i * 4);
  out[(size_t)0 * R_ * R_ + i] = f2bf(v.x);
  out[(size_t)1 * R_ * R_ + i] = f2bf(v.y);
  out[(size_t)2 * R_ * R_ + i] = f2bf(v.z);
  out[(size_t)3 * R_ * R_ + i] = f2bf(v.w);
}

// zero the 3+3 pad rows per batch of padded h1 [B][LP_][R]
__global__ void zero_pads(u16* __restrict__ h1p) {
  int i = blockIdx.x * blockDim.x + threadIdx.x;   // over 24*R_
  if (i >= 24 * R_) return;
  const int rr = i / R_, c = i % R_;
  const int b = rr / 6, k = rr % 6;
  const int row = b * LP_ + (k < 3 ? k : L_ + k);  // rows 0..2 and 2051..2053
  h1p[(size_t)row * R_ + c] = 0;
}

// ---------------- 256-wide 8-phase GEMM ----------------
// C[M, N] = act(A[M,K] * Bm[N,K]^T + bias[N]), bf16 in, fp32 accum.
// BM=256, BN=NF*64 (NF=5 -> 320, NF=4 -> 256), BK=64. 512 threads = 8 waves (2M x 4N).
// Per wave: 128 rows x NF*16 cols = acc[8][NF] of 16x16 frags.
//
// Phases grouped BY K-SLICE so one bF[NF] register set serves two phases (-20 VGPR
// vs bF0+bF1):
//   ph0: ds_read A(half0,k0) + B(all,k0)->bF; stage A1(t+1)->lds[p^1] ; MFMA acc[0..3] x bF
//   ph1: ds_read A(half1,k0)                                          ; MFMA acc[4..7] x bF
//   ph2: ds_read A(half0,k1) + B(all,k1)->bF                          ; MFMA acc[0..3] x bF
//   ph3: ds_read A(half1,k1); stage A0(t+2)+B0..4(t+2)->lds[p] (both regions dead
//        after ph2); vmcnt(NF+2)                                      ; MFMA acc[4..7] x bF
// Each phase: [reads; stages; barrier; lgkmcnt(0); setprio(1); MFMA; setprio(0); barrier].
// Fence audit: per tile issues = 2 (ph0) + NF+2 (ph3); vmcnt(NF+2) at end of ph3 keeps
// only the ph3 batch outstanding => tile t+1 (A1 from ph0-of-t, A0/B from ph3-of-t-1)
// fully resident at t+1 ph0. In-order retirement makes the count exact.
// LDS: per buffer A halves [128][64] + NF B chunks [64][64], 128B rows, chunk-XOR
// swizzle c^(row&7) on stage SOURCE and ds_read (both-sides rule). Bank conflicts
// measured 0.
//
// REGISTER BUDGET: amdgpu_waves_per_eu(2,2) pins the allocator to 2 waves/EU = 256
// VGPR/wave. Without it the backend targeted 4 waves/EU (128 VGPR) and spilled the
// whole accumulator (WRITE_SIZE 41MB -> 637MB measured in r1/r2). LDS=144KB already
// forces 1 WG/CU = 2 waves/EU, so nothing is lost.
template <int NF, int IB>
__device__ __forceinline__ void mfma_block(f32x4 (&acc)[8][NF], const short8 (&aF)[4],
                                           const short8 (&bF)[NF]) {
#pragma unroll
  for (int i = 0; i < 4; ++i)
#pragma unroll
    for (int j = 0; j < NF; ++j)
      acc[IB + i][j] =
          __builtin_amdgcn_mfma_f32_16x16x32_bf16(aF[i], bF[j], acc[IB + i][j], 0, 0, 0);
}

template <int KDIM, int TAPS, int NF, int ACT, int OBF16, int PADOUT>
__global__ __launch_bounds__(512)
__attribute__((amdgpu_waves_per_eu(2, 2)))
void gemm256(const u16* __restrict__ A, const u16* __restrict__ Bm,
             const float* __restrict__ bias, void* __restrict__ Cv, int N) {
  constexpr int NTK = KDIM / 64;
  constexpr int NT  = NTK * TAPS;
  constexpr int BN  = NF * 64;
  constexpr int BUFU16 = 16384 + NF * 4096;      // u16 per buffer (A 32KB + B NF*8KB)
  __shared__ u16 lds[2][BUFU16];

  const int tid  = threadIdx.x;
  const int wave = tid >> 6, lane = tid & 63;
  const int wr = wave >> 2, wc = wave & 3;       // 2 x 4 wave grid
  const int q = lane >> 4, r16 = lane & 15;
  const int rsw = r16 & 7;
  const int bm = blockIdx.x * 256, bn = blockIdx.y * BN;
  const int srow = tid >> 3;                     // 0..63 staging row
  const int schunk = (tid & 7) ^ (srow & 7);     // pre-swizzled source chunk
  const int bbatch = bm >> 11;                   // batch (L_=2048, BM=256 divides)
  const int arow0 = (TAPS == 4) ? (bm + 3 + 6 * bbatch) : bm;

  f32x4 acc[8][NF] = {};

  auto stA = [&](int u, int h) {                 // one A half-tile (128 rows): 2 issues
    const int uc = (u < NT) ? u : (NT - 1);
    const int tap = uc / NTK;
    const int ku  = (uc % NTK) * 64;
    const int sh  = (TAPS == 4) ? (2 * tap - 3) : 0;
    const u16* src = A + (size_t)(arow0 + sh + h * 128) * KDIM + ku + schunk * 8;
    u16* dst = &lds[u & 1][h * 8192 + wave * 512];
#pragma unroll
    for (int s = 0; s < 2; ++s)
      gld16(src + (size_t)(s * 64 + srow) * KDIM, dst + s * 4096);
  };
  auto stB = [&](int u, int j) {                 // one B chunk (64 N-rows): 1 issue
    const int uc = (u < NT) ? u : (NT - 1);
    const int tap = uc / NTK;
    const int ku  = (uc % NTK) * 64;
    const u16* src = Bm + (size_t)tap * R_ * R_ +
                     (size_t)(bn + j * 64 + srow) * KDIM + ku + schunk * 8;
    gld16(src, &lds[u & 1][16384 + j * 4096 + wave * 512]);
  };
  auto ldA = [&](short8 (&f)[4], int p, int half, int k) {
    const int base = half * 8192 + (wr * 64 + r16) * 64 + ((k * 4 + q) ^ rsw) * 8;
#pragma unroll
    for (int i = 0; i < 4; ++i)
      f[i] = *(const short8*)&lds[p][base + i * 1024];
  };
  auto ldB = [&](short8 (&f)[NF], int p, int k) {
    const int base = 16384 + (wc * 16 + r16) * 64 + ((k * 4 + q) ^ rsw) * 8;
#pragma unroll
    for (int j = 0; j < NF; ++j)
      f[j] = *(const short8*)&lds[p][base + j * 4096];
  };

  // ---- prologue: tile0 fully + tile1's A0 and B; A1(1) arrives in t=0 ph0
  stA(0, 0); stA(0, 1);
#pragma unroll
  for (int j = 0; j < NF; ++j) stB(0, j);
  stA(1, 0);
#pragma unroll
  for (int j = 0; j < NF; ++j) stB(1, j);
  asm volatile("s_waitcnt vmcnt(%0)" :: "n"(NF + 2) : "memory");
  SB0();
  BAR();

  short8 aF[4], bF[NF];
  for (int t = 0; t < NT; ++t) {
    const int p = t & 1;
    // ---- phase 0: M-half0 x k0; stage A1(t+1)
    ldA(aF, p, 0, 0);
    ldB(bF, p, 0);
    stA(t + 1, 1);
    BAR(); LGKM0();
    __builtin_amdgcn_s_setprio(1);
    mfma_block<NF, 0>(acc, aF, bF);
    __builtin_amdgcn_s_setprio(0);
    SB0(); BAR();
    // ---- phase 1: M-half1 x k0 (reuses bF)
    ldA(aF, p, 1, 0);
    BAR(); LGKM0();
    __builtin_amdgcn_s_setprio(1);
    mfma_block<NF, 4>(acc, aF, bF);
    __builtin_amdgcn_s_setprio(0);
    SB0(); BAR();
    // ---- phase 2: M-half0 x k1 (reloads bF)
    ldA(aF, p, 0, 1);
    ldB(bF, p, 1);
    BAR(); LGKM0();
    __builtin_amdgcn_s_setprio(1);
    mfma_block<NF, 0>(acc, aF, bF);
    __builtin_amdgcn_s_setprio(0);
    SB0(); BAR();
    // ---- phase 3: M-half1 x k1; stage A0(t+2) + B(t+2) into now-dead regions of lds[p]
    ldA(aF, p, 1, 1);
    stA(t + 2, 0);
#pragma unroll
    for (int j = 0; j < NF; ++j) stB(t + 2, j);
    BAR(); LGKM0();
    __builtin_amdgcn_s_setprio(1);
    mfma_block<NF, 4>(acc, aF, bF);
    __builtin_amdgcn_s_setprio(0);
    asm volatile("s_waitcnt vmcnt(%0)" :: "n"(NF + 2) : "memory");
    SB0(); BAR();
  }

  // ---- epilogue
#pragma unroll
  for (int i = 0; i < 8; ++i) {
    const int rb  = ((i & 4) ? 128 : 0) + wr * 64 + (i & 3) * 16;
    const int row = bm + rb + q * 4;
    const int orow = PADOUT ? (row + 3 + 6 * bbatch) : row;
#pragma unroll
    for (int j = 0; j < NF; ++j) {
      const int col = bn + j * 64 + wc * 16 + r16;
      const float bv = bias[col];
#pragma unroll
      for (int rr = 0; rr < 4; ++rr) {
        float v = acc[i][j][rr] + bv;
        if (ACT == 1) v = v / (1.f + __expf(-v));
        const size_t off = (size_t)(orow + rr) * N + col;
        if (OBF16) ((u16*)Cv)[off] = f2bf(v);
        else       ((float*)Cv)[off] = v;
      }
    }
  }
}

// ---------------- RG-LRU elementwise: build (a, b) fp32 ----------------
__global__ void gate_ew(const u16* __restrict__ gab, const u16* __restrict__ gib,
                        const u16* __restrict__ h2b, const float* __restrict__ lam,
                        float* __restrict__ a32, float* __restrict__ b32) {
  int idx = blockIdx.x * blockDim.x + threadIdx.x;
  if (idx >= BL_ * R_) return;
  const int r = idx % R_;
  const float ga = bf2f(gab[idx]);
  const float gi = bf2f(gib[idx]);
  const float h2 = bf2f(h2b[idx]);
  const float rr = 1.f / (1.f + __expf(-ga));
  const float ii = 1.f / (1.f + __expf(-gi));
  const float lm = lam[r];
  const float sp = log1pf(__expf(lm));          // softplus, lam in [0.5,2]
  const float log_a = -8.f * rr * sp;
  const float a  = __expf(log_a);
  const float e2 = __expf(2.f * log_a);
  const float mult = sqrtf(fmaxf(1.f - e2, 0.f));
  a32[idx] = a;
  b32[idx] = mult * ii * h2;
}

// ---------------- chunked scan: 3 passes ----------------
__global__ void scan_pass1(const float* __restrict__ a32, const float* __restrict__ b32,
                           float* __restrict__ Aprod, float* __restrict__ Hend) {
  int t = blockIdx.x * blockDim.x + threadIdx.x;   // over CHK_*B_*R_
  if (t >= CHK_ * B_ * R_) return;
  const int c = t / (B_ * R_), br = t % (B_ * R_);
  const int b = br / R_, r = br % R_;
  size_t idx = ((size_t)b * L_ + c * CLEN_) * R_ + r;
  float Ap = 1.f, h = 0.f;
  for (int l = 0; l < CLEN_; ++l) {
    const float a = a32[idx], bb = b32[idx];
    Ap *= a;
    h = a * h + bb;
    idx += R_;
  }
  Aprod[t] = Ap;
  Hend[t]  = h;
}

__global__ void scan_pass2(const float* __restrict__ Aprod, float* __restrict__ Hend) {
  int br = blockIdx.x * blockDim.x + threadIdx.x;
  if (br >= B_ * R_) return;
  float h = Hend[br];                               // chunk 0 end state
  for (int c = 1; c < CHK_; ++c) {
    const int i = c * (B_ * R_) + br;
    h = Hend[i] + Aprod[i] * h;
    Hend[i] = h;
  }
}

__global__ void scan_pass3(const float* __restrict__ a32, const float* __restrict__ b32,
                           const float* __restrict__ Hend, u16* __restrict__ hs) {
  int t = blockIdx.x * blockDim.x + threadIdx.x;
  if (t >= CHK_ * B_ * R_) return;
  const int c = t / (B_ * R_), br = t % (B_ * R_);
  const int b = br / R_, r = br % R_;
  float h = (c == 0) ? 0.f : Hend[(size_t)(c - 1) * (B_ * R_) + br];
  size_t idx = ((size_t)b * L_ + c * CLEN_) * R_ + r;
  for (int l = 0; l < CLEN_; ++l) {
    h = a32[idx] * h + b32[idx];
    hs[idx] = f2bf(h);
    idx += R_;
  }
}

// ---------------- launcher ----------------
extern "C" void kernel_launch(void* const* d_in, const int* in_sizes, int n_in,
                              void* d_out, int out_size, void* d_ws, size_t ws_size,
                              hipStream_t stream) {
  (void)in_sizes; (void)n_in; (void)out_size; (void)ws_size;
  const float* x   = (const float*)d_in[0];
  const float* w1  = (const float*)d_in[1];
  const float* b1  = (const float*)d_in[2];
  const float* cw  = (const float*)d_in[3];
  const float* cb  = (const float*)d_in[4];
  const float* wa  = (const float*)d_in[5];
  const float* ba  = (const float*)d_in[6];
  const float* wx  = (const float*)d_in[7];
  const float* bx  = (const float*)d_in[8];
  const float* lam = (const float*)d_in[9];
  const float* w2  = (const float*)d_in[10];
  const float* b2  = (const float*)d_in[11];

  char* ws = (char*)d_ws;
  size_t o = 0;
  auto alloc = [&](size_t bytes) { char* p = ws + o; o += (bytes + 255) & ~255ull; return p; };

  u16* w2b = (u16*)alloc((size_t)D_ * R_ * 2);
  u16* wab = (u16*)alloc((size_t)R_ * R_ * 2);
  u16* wxb = (u16*)alloc((size_t)R_ * R_ * 2);
  char* a32p = ws + o;                       // overlay: xb+w1b+cwb (dead by then) = 96.5MB >= 84MB
  u16* xb  = (u16*)alloc((size_t)BL_ * D_ * 2);
  u16* w1b = (u16*)alloc((size_t)R_ * D_ * 2);
  u16* cwb = (u16*)alloc((size_t)4 * R_ * R_ * 2);
  char* b32p = ws + o;                       // overlay: h1p (dead after conv) + extra = 84MB
  u16* h1p = (u16*)alloc((size_t)B_ * LP_ * R_ * 2);          // padded h1
  alloc((size_t)BL_ * R_ * 4 - (size_t)B_ * LP_ * R_ * 2);    // extra tail of b32 overlay
  u16* h2b = (u16*)alloc((size_t)BL_ * R_ * 2);
  u16* gab = (u16*)alloc((size_t)BL_ * R_ * 2);
  u16* gib = (u16*)alloc((size_t)BL_ * R_ * 2);
  float* Aprod = (float*)alloc((size_t)CHK_ * B_ * R_ * 4);
  float* Hend  = (float*)alloc((size_t)CHK_ * B_ * R_ * 4);
  float* a32 = (float*)a32p;
  float* b32 = (float*)b32p;
  u16* hsb = gab;                            // reuse after gate_ew consumed it

  cvt_bf16<<<4096, 256, 0, stream>>>(x,  xb,  BL_ * D_);
  cvt_bf16<<<2048, 256, 0, stream>>>(w1, w1b, R_ * D_);
  cvt_bf16<<<2048, 256, 0, stream>>>(wa, wab, R_ * R_);
  cvt_bf16<<<2048, 256, 0, stream>>>(wx, wxb, R_ * R_);
  cvt_bf16<<<2048, 256, 0, stream>>>(w2, w2b, D_ * R_);
  cvt_convw<<<(R_ * R_ + 255) / 256, 256, 0, stream>>>(cw, cwb);
  zero_pads<<<(24 * R_ + 255) / 256, 256, 0, stream>>>(h1p);

  // linear1 + silu -> padded h1 (rows +3+6*batch)
  gemm256<2048, 1, 5, 1, 1, 1><<<dim3(32, 8), 512, 0, stream>>>(xb, w1b, b1, h1p, R_);
  // temporal conv: K' = 4*R GEMM over padded h1 (tap folded into K-tiles)
  gemm256<2560, 4, 5, 0, 1, 0><<<dim3(32, 8), 512, 0, stream>>>(h1p, cwb, cb, h2b, R_);
  // gates
  gemm256<2560, 1, 5, 0, 1, 0><<<dim3(32, 8), 512, 0, stream>>>(h2b, wab, ba, gab, R_);
  gemm256<2560, 1, 5, 0, 1, 0><<<dim3(32, 8), 512, 0, stream>>>(h2b, wxb, bx, gib, R_);
  // a,b for recurrence
  gate_ew<<<(BL_ * R_ + 255) / 256, 256, 0, stream>>>(gab, gib, h2b, lam, a32, b32);
  // linear recurrence (chunked, 3 passes)
  scan_pass1<<<(CHK_ * B_ * R_ + 255) / 256, 256, 0, stream>>>(a32, b32, Aprod, Hend);
  scan_pass2<<<(B_ * R_ + 255) / 256, 256, 0, stream>>>(Aprod, Hend);
  scan_pass3<<<(CHK_ * B_ * R_ + 255) / 256, 256, 0, stream>>>(a32, b32, Hend, hsb);
  // linear2 -> d_out (fp32), N=2048 uses NF=4 (grid 32x8 exact)
  gemm256<2560, 1, 4, 0, 0, 0><<<dim3(32, 8), 512, 0, stream>>>(hsb, w2b, b2, d_out, D_);
}